// Round 5
// baseline (534.412 us; speedup 1.0000x reference)
//
#include <hip/hip_runtime.h>

// SimpleDHSRNN fused forward, round 5.
// grid = 512 x (M=16 rows); block = 256 = 4 waves.
// Stage map: S1 all waves (3-term); S2 waves 2,3 (paired dup-B);
//            S3 waves 0,1 (3-term, 4 n-tiles each); S4 waves 2,3 (paired dup-B).
// ns1/ns2 live in pair-interleaved (hi,lo) dword LDS planes -> b32 writes;
// h1/h2 stay 2-plane b16 (read 3-term by S1/S3).

typedef float f32x4 __attribute__((ext_vector_type(4)));
typedef short s16x8 __attribute__((ext_vector_type(8)));

#define MFMA16(a, b, c) __builtin_amdgcn_mfma_f32_16x16x32_bf16((a), (b), (c), 0, 0, 0)
#define T_STEPS 196
#define S2P 68    // A2p row stride (dwords), mult of 4 for b128 align
#define S4P 132   // A4p row stride (dwords)

__device__ __forceinline__ void split8g(const float* __restrict__ p, s16x8& h, s16x8& l) {
#pragma unroll
    for (int i = 0; i < 8; ++i) {
        float v = p[i];
        unsigned b = __float_as_uint(v);
        float lo = v - __uint_as_float(b & 0xFFFF0000u);
        h[i] = (short)(b >> 16);
        l[i] = (short)(__float_as_uint(lo) >> 16);
    }
}

// Build duplicated-pair B fragments from 4 consecutive f32 weights (16B aligned):
// B1 = [h0,h0,h1,h1,h2,h2,h3,h3], B2 = [l0,l0,l1,l1,l2,l2,l3,l3]
__device__ __forceinline__ void dupB(const float* __restrict__ p, s16x8& B1, s16x8& B2) {
    const f32x4 v = *reinterpret_cast<const f32x4*>(p);
#pragma unroll
    for (int i = 0; i < 4; ++i) {
        float vv = v[i];
        unsigned b = __float_as_uint(vv);
        float lo = vv - __uint_as_float(b & 0xFFFF0000u);
        short h = (short)(b >> 16);
        short lb = (short)(__float_as_uint(lo) >> 16);
        B1[2 * i] = h;  B1[2 * i + 1] = h;
        B2[2 * i] = lb; B2[2 * i + 1] = lb;
    }
}

// pack fp32 -> dword (lo16 of dword = hi-bf16, hi16 = lo-bf16)
__device__ __forceinline__ unsigned packhl(float v) {
    unsigned b = __float_as_uint(v);
    float lo = v - __uint_as_float(b & 0xFFFF0000u);
    return (b >> 16) | (__float_as_uint(lo) & 0xFFFF0000u);
}

__global__ __launch_bounds__(256, 2)
void dhsrnn_mfma(const float* __restrict__ x,
                 const float* __restrict__ r1_bw, const float* __restrict__ r1_bb,
                 const float* __restrict__ r1_ow, const float* __restrict__ r1_ob,
                 const float* __restrict__ r2_bw, const float* __restrict__ r2_bb,
                 const float* __restrict__ r2_ow, const float* __restrict__ r2_ob,
                 const float* __restrict__ cw,    const float* __restrict__ cb,
                 float* __restrict__ out)
{
    __shared__ __align__(16) unsigned short A3h[16 * 104];   // h planes (hi), cols 0-31 h1, 32-95 h2
    __shared__ __align__(16) unsigned short A3l[16 * 104];   // (lo)
    __shared__ __align__(16) unsigned int   A2p[16 * S2P];   // ns1 paired [m][n], n<64
    __shared__ __align__(16) unsigned int   A4p[16 * S4P];   // ns2 paired [m][n], n<128
    __shared__ float XBuf[16];

    const int tid = threadIdx.x;
    const int w   = tid >> 6;
    const int l   = tid & 63;
    const int li  = l & 15;
    const int g   = l >> 4;
    const int row0 = blockIdx.x * 16;

    for (int i = tid; i < 16 * 104; i += 256) { A3h[i] = 0; A3l[i] = 0; }
    if (tid < 16) XBuf[tid] = x[(row0 + tid) * 784];

    // ---- weight fragments ----
    // S1 (all waves): 3-term, N=64, K=32
    const int n1 = w * 16 + li;
    s16x8 B1h, B1l;
    split8g(r1_bw + n1 * 33 + 1 + g * 8, B1h, B1l);
    const float wxn = r1_bw[n1 * 33];
    const float b1n = r1_bb[n1];
    const float a1  = (w < 2) ? 0.3f : 0.7f;

    // Union weight storage: w<2 -> BW[0..23] = S3 (4 tiles x 3 kt x {h,l})
    //                       w>=2 -> BW[0..7] = S2 dup, BW[8..39] = S4 dup
    s16x8 BW[40];
    float b2n[4];                 // S3 biases (w<2)
    float ob1n = 0.0f, ob2n0 = 0.0f, ob2n1 = 0.0f;
    int n2 = 0;

    if (w < 2) {
#pragma unroll
        for (int ft = 0; ft < 4; ++ft) {
            int n3 = (w * 4 + ft) * 16 + li;
            b2n[ft] = r2_bb[n3];
#pragma unroll
            for (int kt = 0; kt < 3; ++kt)
                split8g(r2_bw + n3 * 96 + kt * 32 + g * 8, BW[ft * 6 + kt * 2], BW[ft * 6 + kt * 2 + 1]);
        }
    } else {
        n2 = (w - 2) * 16 + li;
#pragma unroll
        for (int kt = 0; kt < 2; ++kt)
#pragma unroll
            for (int h = 0; h < 2; ++h)
                dupB(r1_ow + n2 * 64 + kt * 32 + h * 16 + 4 * g,
                     BW[kt * 4 + h * 2], BW[kt * 4 + h * 2 + 1]);
        ob1n = r1_ob[n2];
#pragma unroll
        for (int ft = 0; ft < 2; ++ft) {
            int n4 = ((w - 2) * 2 + ft) * 16 + li;
#pragma unroll
            for (int kt = 0; kt < 4; ++kt)
#pragma unroll
                for (int h = 0; h < 2; ++h)
                    dupB(r2_ow + n4 * 128 + kt * 32 + h * 16 + 4 * g,
                         BW[8 + ft * 16 + kt * 4 + h * 2], BW[8 + ft * 16 + kt * 4 + h * 2 + 1]);
        }
        ob2n0 = r2_ob[(w - 2) * 32 + li];
        ob2n1 = r2_ob[(w - 2) * 32 + 16 + li];
    }
    const float a2 = (w == 0) ? 0.3f : 0.7f;   // only used on w<2 (tiles 0-3 vs 4-7)

    // EMA states
    f32x4 s1a = {0.f, 0.f, 0.f, 0.f};
    f32x4 s2a[4];
#pragma unroll
    for (int ft = 0; ft < 4; ++ft) s2a[ft] = (f32x4){0.f, 0.f, 0.f, 0.f};

    __syncthreads();

#pragma unroll 1
    for (int t = 0; t < T_STEPS; ++t) {
        float xnext = 0.0f;
        if (w == 2 && l < 16 && t + 1 < T_STEPS)
            xnext = x[(row0 + l) * 784 + 4 * (t + 1)];

        // ---- S1 (all waves): bo1 = h1 @ W1h^T + x*wx + b; EMA -> A2p paired ----
        {
            const f32x4 xv = *reinterpret_cast<const f32x4*>(&XBuf[4 * g]);
            const s16x8 ah = *reinterpret_cast<const s16x8*>(&A3h[li * 104 + g * 8]);
            const s16x8 al = *reinterpret_cast<const s16x8*>(&A3l[li * 104 + g * 8]);
            f32x4 d = {0.f, 0.f, 0.f, 0.f};
            d = MFMA16(ah, B1h, d);
            d = MFMA16(al, B1h, d);
            d = MFMA16(ah, B1l, d);
#pragma unroll
            for (int r = 0; r < 4; ++r) {
                int m = 4 * g + r;
                float bo = d[r] + b1n + wxn * xv[r];
                float ns = a1 * s1a[r] + (1.0f - a1) * bo;
                s1a[r] = ns;
                A2p[m * S2P + n1] = packhl(ns);
            }
        }
        __syncthreads();

        // ---- S2 (waves 2,3): h1 = relu(ns1 @ ow1^T + ob1), paired dup-B ----
        if (w >= 2) {
            f32x4 d = {0.f, 0.f, 0.f, 0.f};
#pragma unroll
            for (int kt = 0; kt < 2; ++kt)
#pragma unroll
                for (int h = 0; h < 2; ++h) {
                    const s16x8 ap = *reinterpret_cast<const s16x8*>(&A2p[li * S2P + kt * 32 + h * 16 + 4 * g]);
                    d = MFMA16(ap, BW[kt * 4 + h * 2], d);       // (h+l)*Wh
                    d = MFMA16(ap, BW[kt * 4 + h * 2 + 1], d);   // (h+l)*Wl
                }
#pragma unroll
            for (int r = 0; r < 4; ++r) {
                int m = 4 * g + r;
                float hv = fmaxf(d[r] + ob1n, 0.0f);
                unsigned b = __float_as_uint(hv);
                float lo = hv - __uint_as_float(b & 0xFFFF0000u);
                A3h[m * 104 + n2] = (unsigned short)(b >> 16);
                A3l[m * 104 + n2] = (unsigned short)(__float_as_uint(lo) >> 16);
            }
        }
        __syncthreads();

        // ---- S3 (waves 0,1): bo2 = [h1|h2] @ W2b^T + b; EMA -> A4p paired ----
        if (w < 2) {
            f32x4 d3[4];
#pragma unroll
            for (int ft = 0; ft < 4; ++ft) d3[ft] = (f32x4){0.f, 0.f, 0.f, 0.f};
#pragma unroll
            for (int kt = 0; kt < 3; ++kt) {
                const s16x8 ah = *reinterpret_cast<const s16x8*>(&A3h[li * 104 + kt * 32 + g * 8]);
                const s16x8 al = *reinterpret_cast<const s16x8*>(&A3l[li * 104 + kt * 32 + g * 8]);
#pragma unroll
                for (int ft = 0; ft < 4; ++ft) {
                    d3[ft] = MFMA16(ah, BW[ft * 6 + kt * 2], d3[ft]);
                    d3[ft] = MFMA16(al, BW[ft * 6 + kt * 2], d3[ft]);
                    d3[ft] = MFMA16(ah, BW[ft * 6 + kt * 2 + 1], d3[ft]);
                }
            }
#pragma unroll
            for (int ft = 0; ft < 4; ++ft) {
                int n3 = (w * 4 + ft) * 16 + li;
#pragma unroll
                for (int r = 0; r < 4; ++r) {
                    int m = 4 * g + r;
                    float bo = d3[ft][r] + b2n[ft];
                    float ns = a2 * s2a[ft][r] + (1.0f - a2) * bo;
                    s2a[ft][r] = ns;
                    A4p[m * S4P + n3] = packhl(ns);
                }
            }
        }
        __syncthreads();

        // ---- S4 (waves 2,3): h2 = relu(ns2 @ ow2^T + ob2), paired dup-B ----
        if (w >= 2) {
            f32x4 d4[2];
            d4[0] = (f32x4){0.f, 0.f, 0.f, 0.f};
            d4[1] = (f32x4){0.f, 0.f, 0.f, 0.f};
#pragma unroll
            for (int kt = 0; kt < 4; ++kt)
#pragma unroll
                for (int h = 0; h < 2; ++h) {
                    const s16x8 ap = *reinterpret_cast<const s16x8*>(&A4p[li * S4P + kt * 32 + h * 16 + 4 * g]);
                    d4[0] = MFMA16(ap, BW[8 + kt * 4 + h * 2], d4[0]);
                    d4[0] = MFMA16(ap, BW[8 + kt * 4 + h * 2 + 1], d4[0]);
                    d4[1] = MFMA16(ap, BW[24 + kt * 4 + h * 2], d4[1]);
                    d4[1] = MFMA16(ap, BW[24 + kt * 4 + h * 2 + 1], d4[1]);
                }
            float* const hcf = (float*)A2p;   // classifier h2 [16][S2P] floats, last step only
#pragma unroll
            for (int ft = 0; ft < 2; ++ft) {
                int n4 = (w - 2) * 32 + ft * 16 + li;
                float obv = ft ? ob2n1 : ob2n0;
#pragma unroll
                for (int r = 0; r < 4; ++r) {
                    int m = 4 * g + r;
                    float hv = fmaxf(d4[ft][r] + obv, 0.0f);
                    unsigned b = __float_as_uint(hv);
                    float lo = hv - __uint_as_float(b & 0xFFFF0000u);
                    A3h[m * 104 + 32 + n4] = (unsigned short)(b >> 16);
                    A3l[m * 104 + 32 + n4] = (unsigned short)(__float_as_uint(lo) >> 16);
                    if (t == T_STEPS - 1) hcf[m * S2P + n4] = hv;
                }
            }
            if (w == 2 && l < 16) XBuf[l] = xnext;
        }
        __syncthreads();
    }

    // ---- classifier ----
    {
        const float* hcf = (const float*)A2p;
        const int c = tid >> 4;
        const int e = tid & 15;
        if (c < 10) {
            float acc = cb[c];
#pragma unroll 4
            for (int dd = 0; dd < 64; ++dd)
                acc += hcf[e * S2P + dd] * cw[c * 64 + dd];
            out[(row0 + e) * 10 + c] = acc;
        }
    }
}

extern "C" void kernel_launch(void* const* d_in, const int* in_sizes, int n_in,
                              void* d_out, int out_size, void* d_ws, size_t ws_size,
                              hipStream_t stream) {
    const float* x     = (const float*)d_in[0];
    const float* r1_bw = (const float*)d_in[1];
    const float* r1_bb = (const float*)d_in[2];
    const float* r1_ow = (const float*)d_in[3];
    const float* r1_ob = (const float*)d_in[4];
    const float* r2_bw = (const float*)d_in[5];
    const float* r2_bb = (const float*)d_in[6];
    const float* r2_ow = (const float*)d_in[7];
    const float* r2_ob = (const float*)d_in[8];
    const float* cw    = (const float*)d_in[9];
    const float* cb    = (const float*)d_in[10];
    float* out = (float*)d_out;

    dim3 grid(512);
    dim3 block(256);
    hipLaunchKernelGGL(dhsrnn_mfma, grid, block, 0, stream,
                       x, r1_bw, r1_bb, r1_ow, r1_ob,
                       r2_bw, r2_bb, r2_ow, r2_ob, cw, cb, out);
}

// Round 6
// 284.302 us; speedup vs baseline: 1.8797x; 1.8797x over previous
//
#include <hip/hip_runtime.h>

// SimpleDHSRNN fused forward, round 6.
// Round-4 wave structure (S1/S3/S4 all waves, S2 on waves 0,1) +
//   paired (hi,lo)-dword LDS for ns1/ns2 (b32 writes, dup-B reads)
//   + 3 barriers/step (post-S4 barrier proven redundant).
// grid = 512 x (M=16 rows); block = 256 = 4 waves.

typedef float f32x4 __attribute__((ext_vector_type(4)));
typedef short s16x8 __attribute__((ext_vector_type(8)));

#define MFMA16(a, b, c) __builtin_amdgcn_mfma_f32_16x16x32_bf16((a), (b), (c), 0, 0, 0)
#define T_STEPS 196
#define S2P 68    // A2p row stride (dwords) = 4*17 (odd multiple of 4: good bank phase)
#define S4P 132   // A4p row stride (dwords) = 4*33

// 3-term split: a ~= h + l as bf16 pair
__device__ __forceinline__ void split8g(const float* __restrict__ p, s16x8& h, s16x8& l) {
#pragma unroll
    for (int i = 0; i < 8; ++i) {
        float v = p[i];
        unsigned b = __float_as_uint(v);
        float lo = v - __uint_as_float(b & 0xFFFF0000u);
        h[i] = (short)(b >> 16);
        l[i] = (short)(__float_as_uint(lo) >> 16);
    }
}

// dup-B fragments from 4 consecutive f32 weights:
// Bh = [h0,h0,h1,h1,h2,h2,h3,h3], Bl = [l0,l0,l1,l1,l2,l2,l3,l3]
__device__ __forceinline__ void dupB(const float* __restrict__ p, s16x8& Bh, s16x8& Bl) {
    const f32x4 v = *reinterpret_cast<const f32x4*>(p);
#pragma unroll
    for (int i = 0; i < 4; ++i) {
        float vv = v[i];
        unsigned b = __float_as_uint(vv);
        float lo = vv - __uint_as_float(b & 0xFFFF0000u);
        short h  = (short)(b >> 16);
        short lb = (short)(__float_as_uint(lo) >> 16);
        Bh[2 * i] = h;  Bh[2 * i + 1] = h;
        Bl[2 * i] = lb; Bl[2 * i + 1] = lb;
    }
}

// fp32 -> dword: low16 = hi-bf16, high16 = lo-bf16 (short0=hi, short1=lo)
__device__ __forceinline__ unsigned packhl(float v) {
    unsigned b = __float_as_uint(v);
    float lo = v - __uint_as_float(b & 0xFFFF0000u);
    return (b >> 16) | (__float_as_uint(lo) & 0xFFFF0000u);
}

__global__ __launch_bounds__(256, 2)
void dhsrnn_mfma(const float* __restrict__ x,
                 const float* __restrict__ r1_bw, const float* __restrict__ r1_bb,
                 const float* __restrict__ r1_ow, const float* __restrict__ r1_ob,
                 const float* __restrict__ r2_bw, const float* __restrict__ r2_bb,
                 const float* __restrict__ r2_ow, const float* __restrict__ r2_ob,
                 const float* __restrict__ cw,    const float* __restrict__ cb,
                 float* __restrict__ out)
{
    __shared__ __align__(16) unsigned short A3h[16 * 104];   // h planes (hi): cols 0-31 h1, 32-95 h2
    __shared__ __align__(16) unsigned short A3l[16 * 104];   // (lo)
    __shared__ __align__(16) unsigned int   A2p[16 * S2P];   // ns1 paired [m][n], n<64
    __shared__ __align__(16) unsigned int   A4p[16 * S4P];   // ns2 paired [m][n], n<128
    __shared__ float XBuf[16];

    const int tid = threadIdx.x;
    const int w   = tid >> 6;
    const int l   = tid & 63;
    const int li  = l & 15;
    const int g   = l >> 4;
    const int row0 = blockIdx.x * 16;

    for (int i = tid; i < 16 * 104; i += 256) { A3h[i] = 0; A3l[i] = 0; }
    if (tid < 16) XBuf[tid] = x[(row0 + tid) * 784];

    // ---- weight fragments (separate named arrays, constant indices only) ----
    // S1 (all waves): 3-term, N=64, K=32
    const int n1 = w * 16 + li;
    s16x8 B1h, B1l;
    split8g(r1_bw + n1 * 33 + 1 + g * 8, B1h, B1l);
    const float wxn = r1_bw[n1 * 33];
    const float b1n = r1_bb[n1];
    const float a1  = (w < 2) ? 0.3f : 0.7f;

    // S2 (waves 0,1): paired dup-B, N=32, K=64 logical -> 4 phys tiles
    const int n2 = (w & 1) * 16 + li;
    s16x8 B2d[4][2];
    float ob1n = 0.0f;
    if (w < 2) {
#pragma unroll
        for (int tk = 0; tk < 4; ++tk)
            dupB(r1_ow + n2 * 64 + tk * 16 + 4 * g, B2d[tk][0], B2d[tk][1]);
        ob1n = r1_ob[n2];
    }

    // S3 (all waves): 3-term, N=128 (2 n-tiles/wave), K=96
    s16x8 B3h[2][3], B3l[2][3];
    float b2n[2];
#pragma unroll
    for (int fn = 0; fn < 2; ++fn) {
        int n3 = (2 * w + fn) * 16 + li;
        b2n[fn] = r2_bb[n3];
#pragma unroll
        for (int kt = 0; kt < 3; ++kt)
            split8g(r2_bw + n3 * 96 + kt * 32 + g * 8, B3h[fn][kt], B3l[fn][kt]);
    }
    const float a2 = (w < 2) ? 0.3f : 0.7f;

    // S4 (all waves): paired dup-B, N=64, K=128 logical -> 8 phys tiles
    const int n4 = w * 16 + li;
    s16x8 B4d[8][2];
#pragma unroll
    for (int tk = 0; tk < 8; ++tk)
        dupB(r2_ow + n4 * 128 + tk * 16 + 4 * g, B4d[tk][0], B4d[tk][1]);
    const float ob2n = r2_ob[n4];

    // persistent EMA states (fp32, acc layout row m = 4g + r)
    f32x4 s1a = {0.f, 0.f, 0.f, 0.f};
    f32x4 s2a[2];
    s2a[0] = (f32x4){0.f, 0.f, 0.f, 0.f};
    s2a[1] = (f32x4){0.f, 0.f, 0.f, 0.f};

    __syncthreads();

#pragma unroll 1
    for (int t = 0; t < T_STEPS; ++t) {
        float xnext = 0.0f;
        if (w == 2 && l < 16 && t + 1 < T_STEPS)
            xnext = x[(row0 + l) * 784 + 4 * (t + 1)];

        // ---- S1 (all): bo1 = h1 @ W1h^T + x*wx + b; EMA -> A2p (b32 paired) ----
        {
            const f32x4 xv = *reinterpret_cast<const f32x4*>(&XBuf[4 * g]);
            const s16x8 ah = *reinterpret_cast<const s16x8*>(&A3h[li * 104 + g * 8]);
            const s16x8 al = *reinterpret_cast<const s16x8*>(&A3l[li * 104 + g * 8]);
            f32x4 d = {0.f, 0.f, 0.f, 0.f};
            d = MFMA16(ah, B1h, d);
            d = MFMA16(al, B1h, d);
            d = MFMA16(ah, B1l, d);
#pragma unroll
            for (int r = 0; r < 4; ++r) {
                int m = 4 * g + r;
                float bo = d[r] + b1n + wxn * xv[r];
                float ns = a1 * s1a[r] + (1.0f - a1) * bo;
                s1a[r] = ns;
                A2p[m * S2P + n1] = packhl(ns);
            }
        }
        __syncthreads();   // #1: A2p ready; S1's A3/XBuf reads fenced

        // ---- S2 (waves 0,1): h1 = relu(ns1 @ ow1^T + ob1), paired dup-B ----
        if (w < 2) {
            f32x4 d = {0.f, 0.f, 0.f, 0.f};
#pragma unroll
            for (int tk = 0; tk < 4; ++tk) {
                const s16x8 ap = *reinterpret_cast<const s16x8*>(&A2p[li * S2P + tk * 16 + 4 * g]);
                d = MFMA16(ap, B2d[tk][0], d);   // (h+l)*Wh
                d = MFMA16(ap, B2d[tk][1], d);   // (h+l)*Wl
            }
#pragma unroll
            for (int r = 0; r < 4; ++r) {
                int m = 4 * g + r;
                float hv = fmaxf(d[r] + ob1n, 0.0f);
                unsigned b = __float_as_uint(hv);
                float lo = hv - __uint_as_float(b & 0xFFFF0000u);
                A3h[m * 104 + n2] = (unsigned short)(b >> 16);
                A3l[m * 104 + n2] = (unsigned short)(__float_as_uint(lo) >> 16);
            }
        }
        __syncthreads();   // #2: h1 ready

        // ---- S3 (all): bo2 = [h1|h2] @ W2b^T + b; EMA -> A4p (b32 paired) ----
        {
            f32x4 d3[2];
            d3[0] = (f32x4){0.f, 0.f, 0.f, 0.f};
            d3[1] = (f32x4){0.f, 0.f, 0.f, 0.f};
#pragma unroll
            for (int kt = 0; kt < 3; ++kt) {
                const s16x8 ah = *reinterpret_cast<const s16x8*>(&A3h[li * 104 + kt * 32 + g * 8]);
                const s16x8 al = *reinterpret_cast<const s16x8*>(&A3l[li * 104 + kt * 32 + g * 8]);
#pragma unroll
                for (int fn = 0; fn < 2; ++fn) {
                    d3[fn] = MFMA16(ah, B3h[fn][kt], d3[fn]);
                    d3[fn] = MFMA16(al, B3h[fn][kt], d3[fn]);
                    d3[fn] = MFMA16(ah, B3l[fn][kt], d3[fn]);
                }
            }
#pragma unroll
            for (int fn = 0; fn < 2; ++fn) {
                int n3 = (2 * w + fn) * 16 + li;
#pragma unroll
                for (int r = 0; r < 4; ++r) {
                    int m = 4 * g + r;
                    float bo = d3[fn][r] + b2n[fn];
                    float ns = a2 * s2a[fn][r] + (1.0f - a2) * bo;
                    s2a[fn][r] = ns;
                    A4p[m * S4P + n3] = packhl(ns);
                }
            }
            if (w == 2 && l < 16) XBuf[l] = xnext;   // commit x(t+1); S1 reads fenced by #1
        }
        __syncthreads();   // #3: A4p + XBuf ready

        // ---- S4 (all): h2 = relu(ns2 @ ow2^T + ob2), paired dup-B ----
        {
            f32x4 d4 = {0.f, 0.f, 0.f, 0.f};
#pragma unroll
            for (int tk = 0; tk < 8; ++tk) {
                const s16x8 ap = *reinterpret_cast<const s16x8*>(&A4p[li * S4P + tk * 16 + 4 * g]);
                d4 = MFMA16(ap, B4d[tk][0], d4);
                d4 = MFMA16(ap, B4d[tk][1], d4);
            }
            float* const hcf = (float*)A2p;   // classifier h2 [16][S2P] floats (last step only)
#pragma unroll
            for (int r = 0; r < 4; ++r) {
                int m = 4 * g + r;
                float hv = fmaxf(d4[r] + ob2n, 0.0f);
                unsigned b = __float_as_uint(hv);
                float lo = hv - __uint_as_float(b & 0xFFFF0000u);
                A3h[m * 104 + 32 + n4] = (unsigned short)(b >> 16);
                A3l[m * 104 + 32 + n4] = (unsigned short)(__float_as_uint(lo) >> 16);
                if (t == T_STEPS - 1) hcf[m * S2P + n4] = hv;
            }
        }
        // no barrier: S4(t) vs S3(t+1) ordered by barriers #1/#2 of step t+1
    }
    __syncthreads();   // hcf ready for classifier

    // ---- classifier: out[b][c] = h2 . cw[c] + cb[c] ----
    {
        const float* hcf = (const float*)A2p;
        const int c = tid >> 4;
        const int e = tid & 15;
        if (c < 10) {
            float acc = cb[c];
#pragma unroll 4
            for (int dd = 0; dd < 64; ++dd)
                acc += hcf[e * S2P + dd] * cw[c * 64 + dd];
            out[(row0 + e) * 10 + c] = acc;
        }
    }
}

extern "C" void kernel_launch(void* const* d_in, const int* in_sizes, int n_in,
                              void* d_out, int out_size, void* d_ws, size_t ws_size,
                              hipStream_t stream) {
    const float* x     = (const float*)d_in[0];
    const float* r1_bw = (const float*)d_in[1];
    const float* r1_bb = (const float*)d_in[2];
    const float* r1_ow = (const float*)d_in[3];
    const float* r1_ob = (const float*)d_in[4];
    const float* r2_bw = (const float*)d_in[5];
    const float* r2_bb = (const float*)d_in[6];
    const float* r2_ow = (const float*)d_in[7];
    const float* r2_ob = (const float*)d_in[8];
    const float* cw    = (const float*)d_in[9];
    const float* cb    = (const float*)d_in[10];
    float* out = (float*)d_out;

    dim3 grid(512);
    dim3 block(256);
    hipLaunchKernelGGL(dhsrnn_mfma, grid, block, 0, stream,
                       x, r1_bw, r1_bb, r1_ow, r1_ob,
                       r2_bw, r2_bb, r2_ow, r2_ob, cw, cb, out);
}

// Round 7
// 190.929 us; speedup vs baseline: 2.7990x; 1.4890x over previous
//
#include <hip/hip_runtime.h>

// SimpleDHSRNN fused forward, round 7: algebraic cell fusion.
// h_cell = relu(Wo·s_new + ob), s_new = per-branch EMA of (Wb·ci + bb)
//   => v_k := Wo_k·s_k obeys v_k(t) = alpha_k v_k(t-1) + (1-alpha_k)(M_k·ci(t) + c_k),
//      M_k = Wo_k·Wb_k (precomputed fp32 in d_ws), h = relu(v_a + v_b + ob).
// 2 stages/step, 2 barriers/step. grid = 512 x (M=16 rows); block = 256 = 4 waves.
// Stage1 (layer1, waves 0,1): N=32 per branch; Stage2 (layer2, all waves): N=64 per branch.
// Activations h1/h2 in LDS as bf16 hi/lo planes; h2 double-buffered (same-stage r/w).

typedef float f32x4 __attribute__((ext_vector_type(4)));
typedef short s16x8 __attribute__((ext_vector_type(8)));

#define MFMA16(a, b, c) __builtin_amdgcn_mfma_f32_16x16x32_bf16((a), (b), (c), 0, 0, 0)
#define T_STEPS 196
#define S1S 40    // H1 plane row stride (ushorts): 80 B, 16B-aligned rows
#define S2S 72    // H2 plane row stride (ushorts): 144 B, 16B-aligned rows

// d_ws layout (floats)
#define WS_M1H 0        // [2][32][32]  M1 h-columns (fused W1o·W1b, cols 1..32 of ci)
#define WS_M1X 2048     // [2][32]      M1 x-column
#define WS_C1  2112     // [2][32]      fused bias W1o_k · r1_bb[k]
#define WS_M2  2176     // [2][64][96]  M2 (fused W2o·W2b)
#define WS_C2  14464    // [2][64]      fused bias
#define WS_TOTAL 14592  // 58368 bytes

__global__ void prep_fuse(const float* __restrict__ r1_bw, const float* __restrict__ r1_bb,
                          const float* __restrict__ r1_ow, const float* __restrict__ r2_bw,
                          const float* __restrict__ r2_bb, const float* __restrict__ r2_ow,
                          float* __restrict__ ws)
{
    int idx = blockIdx.x * 256 + threadIdx.x;
    if (idx >= WS_TOTAL) return;
    float acc = 0.0f;
    if (idx < WS_M1X) {                     // M1h[kb][n][k]
        int kb = idx >> 10, rem = idx & 1023, n = rem >> 5, k = rem & 31;
        for (int j = 0; j < 32; ++j)
            acc += r1_ow[n * 64 + kb * 32 + j] * r1_bw[(kb * 32 + j) * 33 + 1 + k];
    } else if (idx < WS_C1) {               // m1x[kb][n]
        int r = idx - WS_M1X; int kb = r >> 5, n = r & 31;
        for (int j = 0; j < 32; ++j)
            acc += r1_ow[n * 64 + kb * 32 + j] * r1_bw[(kb * 32 + j) * 33];
    } else if (idx < WS_M2) {               // c1[kb][n]
        int r = idx - WS_C1; int kb = r >> 5, n = r & 31;
        for (int j = 0; j < 32; ++j)
            acc += r1_ow[n * 64 + kb * 32 + j] * r1_bb[kb * 32 + j];
    } else if (idx < WS_C2) {               // M2[kb][n][k]
        int r = idx - WS_M2; int kb = r / 6144; int r2 = r - kb * 6144;
        int n = r2 / 96, k = r2 - n * 96;
        for (int j = 0; j < 64; ++j)
            acc += r2_ow[n * 128 + kb * 64 + j] * r2_bw[(kb * 64 + j) * 96 + k];
    } else {                                // c2[kb][n]
        int r = idx - WS_C2; int kb = r >> 6, n = r & 63;
        for (int j = 0; j < 64; ++j)
            acc += r2_ow[n * 128 + kb * 64 + j] * r2_bb[kb * 64 + j];
    }
    ws[idx] = acc;
}

// 3-term split: a ~= h + l as bf16 pair
__device__ __forceinline__ void split8g(const float* __restrict__ p, s16x8& h, s16x8& l) {
#pragma unroll
    for (int i = 0; i < 8; ++i) {
        float v = p[i];
        unsigned b = __float_as_uint(v);
        float lo = v - __uint_as_float(b & 0xFFFF0000u);
        h[i] = (short)(b >> 16);
        l[i] = (short)(__float_as_uint(lo) >> 16);
    }
}

__global__ __launch_bounds__(256, 2)
void dhsrnn_fused2(const float* __restrict__ x, const float* __restrict__ ws,
                   const float* __restrict__ r1_ob, const float* __restrict__ r2_ob,
                   const float* __restrict__ cw, const float* __restrict__ cb,
                   float* __restrict__ out)
{
    __shared__ __align__(16) unsigned short H1h[16 * S1S], H1l[16 * S1S];
    __shared__ __align__(16) unsigned short H2h[2 * 16 * S2S], H2l[2 * 16 * S2S];
    __shared__ float XBuf[16];
    __shared__ float hcf[16 * 68];   // fp32 h2 for classifier (last step only)

    const int tid = threadIdx.x;
    const int w   = tid >> 6;
    const int l   = tid & 63;
    const int li  = l & 15;
    const int g   = l >> 4;
    const int row0 = blockIdx.x * 16;

    for (int i = tid; i < 16 * S1S; i += 256) { H1h[i] = 0; H1l[i] = 0; }
    for (int i = tid; i < 2 * 16 * S2S; i += 256) { H2h[i] = 0; H2l[i] = 0; }
    if (tid < 16) XBuf[tid] = x[(row0 + tid) * 784];

    // ---- stage-1 weights (waves 0,1): fused layer-1, N=32 per branch, K=32 ----
    const int n2 = (w & 1) * 16 + li;
    s16x8 B1ah, B1al, B1bh, B1bl;
    float m1xa = 0.f, m1xb = 0.f, c1a = 0.f, c1b = 0.f, ob1n = 0.f;
    if (w < 2) {
        split8g(ws + WS_M1H + 0 * 1024 + n2 * 32 + g * 8, B1ah, B1al);
        split8g(ws + WS_M1H + 1 * 1024 + n2 * 32 + g * 8, B1bh, B1bl);
        m1xa = ws[WS_M1X + n2];      m1xb = ws[WS_M1X + 32 + n2];
        c1a  = ws[WS_C1 + n2];       c1b  = ws[WS_C1 + 32 + n2];
        ob1n = r1_ob[n2];
    }

    // ---- stage-2 weights (all waves): fused layer-2, N=64 per branch, K=96 ----
    const int n4 = w * 16 + li;
    s16x8 B2ah[3], B2al[3], B2bh[3], B2bl[3];
#pragma unroll
    for (int kt = 0; kt < 3; ++kt) {
        split8g(ws + WS_M2 + 0 * 6144 + n4 * 96 + kt * 32 + g * 8, B2ah[kt], B2al[kt]);
        split8g(ws + WS_M2 + 1 * 6144 + n4 * 96 + kt * 32 + g * 8, B2bh[kt], B2bl[kt]);
    }
    const float c2a = ws[WS_C2 + n4], c2b = ws[WS_C2 + 64 + n4];
    const float ob2n = r2_ob[n4];

    // persistent fused EMA states v = Wo·s (fp32, acc layout m = 4g + r)
    f32x4 va  = {0.f, 0.f, 0.f, 0.f}, vb  = {0.f, 0.f, 0.f, 0.f};
    f32x4 va2 = {0.f, 0.f, 0.f, 0.f}, vb2 = {0.f, 0.f, 0.f, 0.f};

    __syncthreads();

#pragma unroll 1
    for (int t = 0; t < T_STEPS; ++t) {
        float xnext = 0.0f;
        if (w == 2 && l < 16 && t + 1 < T_STEPS)
            xnext = x[(row0 + l) * 784 + 4 * (t + 1)];

        // ---- Stage 1 (waves 0,1): layer-1 fused. h1 = relu(va+vb+ob1) ----
        if (w < 2) {
            const s16x8 ah = *reinterpret_cast<const s16x8*>(&H1h[li * S1S + g * 8]);
            const s16x8 al = *reinterpret_cast<const s16x8*>(&H1l[li * S1S + g * 8]);
            f32x4 d = {0.f, 0.f, 0.f, 0.f};
            f32x4 e = {0.f, 0.f, 0.f, 0.f};
            d = MFMA16(ah, B1ah, d);
            d = MFMA16(al, B1ah, d);
            d = MFMA16(ah, B1al, d);
            e = MFMA16(ah, B1bh, e);
            e = MFMA16(al, B1bh, e);
            e = MFMA16(ah, B1bl, e);
            const f32x4 xv = *reinterpret_cast<const f32x4*>(&XBuf[4 * g]);
#pragma unroll
            for (int r = 0; r < 4; ++r) {
                int m = 4 * g + r;
                float za = d[r] + c1a + m1xa * xv[r];
                va[r] = 0.3f * va[r] + 0.7f * za;
                float zb = e[r] + c1b + m1xb * xv[r];
                vb[r] = 0.7f * vb[r] + 0.3f * zb;
                float h = fmaxf(va[r] + vb[r] + ob1n, 0.0f);
                unsigned b = __float_as_uint(h);
                float lo = h - __uint_as_float(b & 0xFFFF0000u);
                H1h[m * S1S + n2] = (unsigned short)(b >> 16);
                H1l[m * S1S + n2] = (unsigned short)(__float_as_uint(lo) >> 16);
            }
        }
        __syncthreads();   // #1: h1(t) ready

        // ---- Stage 2 (all waves): layer-2 fused. h2 = relu(va2+vb2+ob2) ----
        {
            const int rb  = (t & 1) * (16 * S2S);        // read h2(t-1)
            const int wbo = ((t & 1) ^ 1) * (16 * S2S);  // write h2(t)
            f32x4 d = {0.f, 0.f, 0.f, 0.f};
            f32x4 e = {0.f, 0.f, 0.f, 0.f};
            {   // kt0: ci2 cols 0-31 = h1
                const s16x8 ah = *reinterpret_cast<const s16x8*>(&H1h[li * S1S + g * 8]);
                const s16x8 al = *reinterpret_cast<const s16x8*>(&H1l[li * S1S + g * 8]);
                d = MFMA16(ah, B2ah[0], d);
                d = MFMA16(al, B2ah[0], d);
                d = MFMA16(ah, B2al[0], d);
                e = MFMA16(ah, B2bh[0], e);
                e = MFMA16(al, B2bh[0], e);
                e = MFMA16(ah, B2bl[0], e);
            }
            {   // kt1: ci2 cols 32-63 = h2[0:32]
                const s16x8 ah = *reinterpret_cast<const s16x8*>(&H2h[rb + li * S2S + g * 8]);
                const s16x8 al = *reinterpret_cast<const s16x8*>(&H2l[rb + li * S2S + g * 8]);
                d = MFMA16(ah, B2ah[1], d);
                d = MFMA16(al, B2ah[1], d);
                d = MFMA16(ah, B2al[1], d);
                e = MFMA16(ah, B2bh[1], e);
                e = MFMA16(al, B2bh[1], e);
                e = MFMA16(ah, B2bl[1], e);
            }
            {   // kt2: ci2 cols 64-95 = h2[32:64]
                const s16x8 ah = *reinterpret_cast<const s16x8*>(&H2h[rb + li * S2S + 32 + g * 8]);
                const s16x8 al = *reinterpret_cast<const s16x8*>(&H2l[rb + li * S2S + 32 + g * 8]);
                d = MFMA16(ah, B2ah[2], d);
                d = MFMA16(al, B2ah[2], d);
                d = MFMA16(ah, B2al[2], d);
                e = MFMA16(ah, B2bh[2], e);
                e = MFMA16(al, B2bh[2], e);
                e = MFMA16(ah, B2bl[2], e);
            }
#pragma unroll
            for (int r = 0; r < 4; ++r) {
                int m = 4 * g + r;
                float za = d[r] + c2a;
                va2[r] = 0.3f * va2[r] + 0.7f * za;
                float zb = e[r] + c2b;
                vb2[r] = 0.7f * vb2[r] + 0.3f * zb;
                float h = fmaxf(va2[r] + vb2[r] + ob2n, 0.0f);
                unsigned b = __float_as_uint(h);
                float lo = h - __uint_as_float(b & 0xFFFF0000u);
                H2h[wbo + m * S2S + n4] = (unsigned short)(b >> 16);
                H2l[wbo + m * S2S + n4] = (unsigned short)(__float_as_uint(lo) >> 16);
                if (t == T_STEPS - 1) hcf[m * 68 + n4] = h;
            }
            if (w == 2 && l < 16) XBuf[l] = xnext;   // x(t+1); stage-1 reads fenced by #2
        }
        __syncthreads();   // #2: h2(t) + XBuf ready
    }

    // ---- classifier: out[b][c] = h2 . cw[c] + cb[c] ----
    {
        const int c = tid >> 4;
        const int e = tid & 15;
        if (c < 10) {
            float acc = cb[c];
#pragma unroll 4
            for (int dd = 0; dd < 64; ++dd)
                acc += hcf[e * 68 + dd] * cw[c * 64 + dd];
            out[(row0 + e) * 10 + c] = acc;
        }
    }
}

extern "C" void kernel_launch(void* const* d_in, const int* in_sizes, int n_in,
                              void* d_out, int out_size, void* d_ws, size_t ws_size,
                              hipStream_t stream) {
    const float* x     = (const float*)d_in[0];
    const float* r1_bw = (const float*)d_in[1];
    const float* r1_bb = (const float*)d_in[2];
    const float* r1_ow = (const float*)d_in[3];
    const float* r1_ob = (const float*)d_in[4];
    const float* r2_bw = (const float*)d_in[5];
    const float* r2_bb = (const float*)d_in[6];
    const float* r2_ow = (const float*)d_in[7];
    const float* r2_ob = (const float*)d_in[8];
    const float* cw    = (const float*)d_in[9];
    const float* cb    = (const float*)d_in[10];
    float* ws  = (float*)d_ws;
    float* out = (float*)d_out;

    hipLaunchKernelGGL(prep_fuse, dim3((WS_TOTAL + 255) / 256), dim3(256), 0, stream,
                       r1_bw, r1_bb, r1_ow, r2_bw, r2_bb, r2_ow, ws);
    hipLaunchKernelGGL(dhsrnn_fused2, dim3(512), dim3(256), 0, stream,
                       x, ws, r1_ob, r2_ob, cw, cb, out);
}

// Round 8
// 175.781 us; speedup vs baseline: 3.0402x; 1.0862x over previous
//
#include <hip/hip_runtime.h>

// SimpleDHSRNN fused forward, round 8: algebraic cell fusion + cross-layer
// software pipeline. In one stage per step: L2(t) on all waves, L1(t+1) on
// waves 2,3 (they reuse the h1(t) A-fragment), x-prefetch on wave 0.
// ONE barrier per step. h1/h2/x double-buffered in LDS.
// grid = 512 x (M=16 rows); block = 256 = 4 waves.

typedef float f32x4 __attribute__((ext_vector_type(4)));
typedef short s16x8 __attribute__((ext_vector_type(8)));

#define MFMA16(a, b, c) __builtin_amdgcn_mfma_f32_16x16x32_bf16((a), (b), (c), 0, 0, 0)
#define T_STEPS 196
#define S1S 40    // H1 plane row stride (ushorts): 80 B
#define S2S 72    // H2 plane row stride (ushorts): 144 B
#define H1B (16 * S1S)   // one h1 buffer (ushorts)
#define H2B (16 * S2S)   // one h2 buffer (ushorts)

// d_ws layout (floats)
#define WS_M1H 0        // [2][32][32]  M1 h-columns (fused W1o·W1b)
#define WS_M1X 2048     // [2][32]      M1 x-column
#define WS_C1  2112     // [2][32]      fused bias W1o_k · r1_bb[k]
#define WS_M2  2176     // [2][64][96]  M2 (fused W2o·W2b)
#define WS_C2  14464    // [2][64]      fused bias
#define WS_TOTAL 14592

__global__ void prep_fuse(const float* __restrict__ r1_bw, const float* __restrict__ r1_bb,
                          const float* __restrict__ r1_ow, const float* __restrict__ r2_bw,
                          const float* __restrict__ r2_bb, const float* __restrict__ r2_ow,
                          float* __restrict__ ws)
{
    int idx = blockIdx.x * 256 + threadIdx.x;
    if (idx >= WS_TOTAL) return;
    float acc = 0.0f;
    if (idx < WS_M1X) {                     // M1h[kb][n][k]
        int kb = idx >> 10, rem = idx & 1023, n = rem >> 5, k = rem & 31;
        for (int j = 0; j < 32; ++j)
            acc += r1_ow[n * 64 + kb * 32 + j] * r1_bw[(kb * 32 + j) * 33 + 1 + k];
    } else if (idx < WS_C1) {               // m1x[kb][n]
        int r = idx - WS_M1X; int kb = r >> 5, n = r & 31;
        for (int j = 0; j < 32; ++j)
            acc += r1_ow[n * 64 + kb * 32 + j] * r1_bw[(kb * 32 + j) * 33];
    } else if (idx < WS_M2) {               // c1[kb][n]
        int r = idx - WS_C1; int kb = r >> 5, n = r & 31;
        for (int j = 0; j < 32; ++j)
            acc += r1_ow[n * 64 + kb * 32 + j] * r1_bb[kb * 32 + j];
    } else if (idx < WS_C2) {               // M2[kb][n][k]
        int r = idx - WS_M2; int kb = r / 6144; int r2 = r - kb * 6144;
        int n = r2 / 96, k = r2 - n * 96;
        for (int j = 0; j < 64; ++j)
            acc += r2_ow[n * 128 + kb * 64 + j] * r2_bw[(kb * 64 + j) * 96 + k];
    } else {                                // c2[kb][n]
        int r = idx - WS_C2; int kb = r >> 6, n = r & 63;
        for (int j = 0; j < 64; ++j)
            acc += r2_ow[n * 128 + kb * 64 + j] * r2_bb[kb * 64 + j];
    }
    ws[idx] = acc;
}

// 3-term split: a ~= h + l as bf16 pair
__device__ __forceinline__ void split8g(const float* __restrict__ p, s16x8& h, s16x8& l) {
#pragma unroll
    for (int i = 0; i < 8; ++i) {
        float v = p[i];
        unsigned b = __float_as_uint(v);
        float lo = v - __uint_as_float(b & 0xFFFF0000u);
        h[i] = (short)(b >> 16);
        l[i] = (short)(__float_as_uint(lo) >> 16);
    }
}

__global__ __launch_bounds__(256, 2)
void dhsrnn_pipe(const float* __restrict__ x, const float* __restrict__ ws,
                 const float* __restrict__ r1_ob, const float* __restrict__ r2_ob,
                 const float* __restrict__ cw, const float* __restrict__ cb,
                 float* __restrict__ out)
{
    __shared__ __align__(16) unsigned short H1h[2 * H1B], H1l[2 * H1B];
    __shared__ __align__(16) unsigned short H2h[2 * H2B], H2l[2 * H2B];
    __shared__ float XBuf[2][16];
    __shared__ float hcf[16 * 68];   // fp32 h2(T-1) for classifier

    const int tid = threadIdx.x;
    const int w   = tid >> 6;
    const int l   = tid & 63;
    const int li  = l & 15;
    const int g   = l >> 4;
    const int row0 = blockIdx.x * 16;

    // ---- L2 weights (all waves): fused layer-2, N=64, K=96 ----
    const int n4 = w * 16 + li;
    s16x8 B2ah[3], B2al[3], B2bh[3], B2bl[3];
#pragma unroll
    for (int kt = 0; kt < 3; ++kt) {
        split8g(ws + WS_M2 + 0 * 6144 + n4 * 96 + kt * 32 + g * 8, B2ah[kt], B2al[kt]);
        split8g(ws + WS_M2 + 1 * 6144 + n4 * 96 + kt * 32 + g * 8, B2bh[kt], B2bl[kt]);
    }
    const float c2a = ws[WS_C2 + n4], c2b = ws[WS_C2 + 64 + n4];
    const float ob2n = r2_ob[n4];

    // ---- L1 weights (waves 2,3): fused layer-1, N=32, K=32 ----
    const int n2 = (w & 1) * 16 + li;    // used on w>=2
    s16x8 B1ah, B1al, B1bh, B1bl;
    float m1xa = 0.f, m1xb = 0.f, c1a = 0.f, c1b = 0.f, ob1n = 0.f;
    if (w >= 2) {
        split8g(ws + WS_M1H + 0 * 1024 + n2 * 32 + g * 8, B1ah, B1al);
        split8g(ws + WS_M1H + 1 * 1024 + n2 * 32 + g * 8, B1bh, B1bl);
        m1xa = ws[WS_M1X + n2];      m1xb = ws[WS_M1X + 32 + n2];
        c1a  = ws[WS_C1 + n2];       c1b  = ws[WS_C1 + 32 + n2];
        ob1n = r1_ob[n2];
    }

    // EMA states (fp32, acc layout m = 4g + r)
    f32x4 va  = {0.f, 0.f, 0.f, 0.f}, vb  = {0.f, 0.f, 0.f, 0.f};     // layer1 (w>=2)
    f32x4 va2 = {0.f, 0.f, 0.f, 0.f}, vb2 = {0.f, 0.f, 0.f, 0.f};     // layer2 (all)

    // ---- prologue: zero h2 buf0, stage x(0),x(1), compute h1(0) into H1 buf0 ----
    for (int i = tid; i < H2B; i += 256) { H2h[i] = 0; H2l[i] = 0; }
    if (tid < 16) {
        XBuf[0][tid] = x[(row0 + tid) * 784];          // x(0)
        XBuf[1][tid] = x[(row0 + tid) * 784 + 4];      // x(1)
    }
    __syncthreads();
    if (w >= 2) {
        const f32x4 xv = *reinterpret_cast<const f32x4*>(&XBuf[0][4 * g]);
#pragma unroll
        for (int r = 0; r < 4; ++r) {
            int m = 4 * g + r;
            float za = c1a + m1xa * xv[r];
            va[r] = 0.7f * za;                  // alpha_a = 0.3, s=0
            float zb = c1b + m1xb * xv[r];
            vb[r] = 0.3f * zb;                  // alpha_b = 0.7
            float h = fmaxf(va[r] + vb[r] + ob1n, 0.0f);
            unsigned b = __float_as_uint(h);
            float lo = h - __uint_as_float(b & 0xFFFF0000u);
            H1h[m * S1S + n2] = (unsigned short)(b >> 16);
            H1l[m * S1S + n2] = (unsigned short)(__float_as_uint(lo) >> 16);
        }
    }
    __syncthreads();

    // ---- pipelined loop: iteration t computes L2(t) and (t<195) L1(t+1) ----
#pragma unroll 1
    for (int t = 0; t < T_STEPS; ++t) {
        const int rb  = (t & 1);
        const int wb  = rb ^ 1;

        // x(t+2) prefetch (wave 0)
        float xnext = 0.0f;
        if (w == 0 && l < 16 && t < T_STEPS - 2)
            xnext = x[(row0 + l) * 784 + 4 * (t + 2)];

        // shared A-frag: h1(t) (kt0 of L2; also A of L1)
        const s16x8 a1h = *reinterpret_cast<const s16x8*>(&H1h[rb * H1B + li * S1S + g * 8]);
        const s16x8 a1l = *reinterpret_cast<const s16x8*>(&H1l[rb * H1B + li * S1S + g * 8]);

        // ---- L2(t): all waves ----
        {
            f32x4 d = {0.f, 0.f, 0.f, 0.f};
            f32x4 e = {0.f, 0.f, 0.f, 0.f};
            d = MFMA16(a1h, B2ah[0], d);
            d = MFMA16(a1l, B2ah[0], d);
            d = MFMA16(a1h, B2al[0], d);
            e = MFMA16(a1h, B2bh[0], e);
            e = MFMA16(a1l, B2bh[0], e);
            e = MFMA16(a1h, B2bl[0], e);
            {   // kt1: h2(t-1)[0:32]
                const s16x8 ah = *reinterpret_cast<const s16x8*>(&H2h[rb * H2B + li * S2S + g * 8]);
                const s16x8 al = *reinterpret_cast<const s16x8*>(&H2l[rb * H2B + li * S2S + g * 8]);
                d = MFMA16(ah, B2ah[1], d);
                d = MFMA16(al, B2ah[1], d);
                d = MFMA16(ah, B2al[1], d);
                e = MFMA16(ah, B2bh[1], e);
                e = MFMA16(al, B2bh[1], e);
                e = MFMA16(ah, B2bl[1], e);
            }
            {   // kt2: h2(t-1)[32:64]
                const s16x8 ah = *reinterpret_cast<const s16x8*>(&H2h[rb * H2B + li * S2S + 32 + g * 8]);
                const s16x8 al = *reinterpret_cast<const s16x8*>(&H2l[rb * H2B + li * S2S + 32 + g * 8]);
                d = MFMA16(ah, B2ah[2], d);
                d = MFMA16(al, B2ah[2], d);
                d = MFMA16(ah, B2al[2], d);
                e = MFMA16(ah, B2bh[2], e);
                e = MFMA16(al, B2bh[2], e);
                e = MFMA16(ah, B2bl[2], e);
            }
#pragma unroll
            for (int r = 0; r < 4; ++r) {
                int m = 4 * g + r;
                float za = d[r] + c2a;
                va2[r] = 0.3f * va2[r] + 0.7f * za;
                float zb = e[r] + c2b;
                vb2[r] = 0.7f * vb2[r] + 0.3f * zb;
                float h = fmaxf(va2[r] + vb2[r] + ob2n, 0.0f);
                unsigned b = __float_as_uint(h);
                float lo = h - __uint_as_float(b & 0xFFFF0000u);
                H2h[wb * H2B + m * S2S + n4] = (unsigned short)(b >> 16);
                H2l[wb * H2B + m * S2S + n4] = (unsigned short)(__float_as_uint(lo) >> 16);
                if (t == T_STEPS - 1) hcf[m * 68 + n4] = h;
            }
        }

        // ---- L1(t+1): waves 2,3 (reuse a1h/a1l) ----
        if (w >= 2 && t < T_STEPS - 1) {
            f32x4 d = {0.f, 0.f, 0.f, 0.f};
            f32x4 e = {0.f, 0.f, 0.f, 0.f};
            d = MFMA16(a1h, B1ah, d);
            d = MFMA16(a1l, B1ah, d);
            d = MFMA16(a1h, B1al, d);
            e = MFMA16(a1h, B1bh, e);
            e = MFMA16(a1l, B1bh, e);
            e = MFMA16(a1h, B1bl, e);
            const f32x4 xv = *reinterpret_cast<const f32x4*>(&XBuf[wb][4 * g]);  // x(t+1)
#pragma unroll
            for (int r = 0; r < 4; ++r) {
                int m = 4 * g + r;
                float za = d[r] + c1a + m1xa * xv[r];
                va[r] = 0.3f * va[r] + 0.7f * za;
                float zb = e[r] + c1b + m1xb * xv[r];
                vb[r] = 0.7f * vb[r] + 0.3f * zb;
                float h = fmaxf(va[r] + vb[r] + ob1n, 0.0f);
                unsigned b = __float_as_uint(h);
                float lo = h - __uint_as_float(b & 0xFFFF0000u);
                H1h[wb * H1B + m * S1S + n2] = (unsigned short)(b >> 16);
                H1l[wb * H1B + m * S1S + n2] = (unsigned short)(__float_as_uint(lo) >> 16);
            }
        }

        // commit x(t+2) into the buffer read two iterations from now
        if (w == 0 && l < 16 && t < T_STEPS - 2) XBuf[rb][l] = xnext;

        __syncthreads();   // h1(t+1), h2(t), x(t+2) all ready
    }

    // ---- classifier: out[b][c] = h2 . cw[c] + cb[c] ----
    {
        const int c = tid >> 4;
        const int e = tid & 15;
        if (c < 10) {
            float acc = cb[c];
#pragma unroll 4
            for (int dd = 0; dd < 64; ++dd)
                acc += hcf[e * 68 + dd] * cw[c * 64 + dd];
            out[(row0 + e) * 10 + c] = acc;
        }
    }
}

extern "C" void kernel_launch(void* const* d_in, const int* in_sizes, int n_in,
                              void* d_out, int out_size, void* d_ws, size_t ws_size,
                              hipStream_t stream) {
    const float* x     = (const float*)d_in[0];
    const float* r1_bw = (const float*)d_in[1];
    const float* r1_bb = (const float*)d_in[2];
    const float* r1_ow = (const float*)d_in[3];
    const float* r1_ob = (const float*)d_in[4];
    const float* r2_bw = (const float*)d_in[5];
    const float* r2_bb = (const float*)d_in[6];
    const float* r2_ow = (const float*)d_in[7];
    const float* r2_ob = (const float*)d_in[8];
    const float* cw    = (const float*)d_in[9];
    const float* cb    = (const float*)d_in[10];
    float* ws  = (float*)d_ws;
    float* out = (float*)d_out;

    hipLaunchKernelGGL(prep_fuse, dim3((WS_TOTAL + 255) / 256), dim3(256), 0, stream,
                       r1_bw, r1_bb, r1_ow, r2_bw, r2_bb, r2_ow, ws);
    hipLaunchKernelGGL(dhsrnn_pipe, dim3(512), dim3(256), 0, stream,
                       x, ws, r1_ob, r2_ob, cw, cb, out);
}